// Round 4
// baseline (42.405 us; speedup 1.0000x reference)
//
#include <hip/hip_runtime.h>
#include <stdint.h>

// DotPredictor: out[e] = dot(h[src[e]], h[dst[e]]), D_FEAT = 64.
// v4: split-feature bf16 tables. h -> hbA (feat 0..31) + hbB (feat 32..63),
// each 3.2 MB contiguous => fully L2-resident per XCD. Two gather passes
// (separate dispatches) so only one 3.2 MB table is hot at a time.

__device__ __forceinline__ float bf16w_dot(uint32_t wa, uint32_t wb, float acc) {
    float alo = __uint_as_float(wa << 16);
    float ahi = __uint_as_float(wa & 0xffff0000u);
    float blo = __uint_as_float(wb << 16);
    float bhi = __uint_as_float(wb & 0xffff0000u);
    acc = fmaf(alo, blo, acc);
    acc = fmaf(ahi, bhi, acc);
    return acc;
}

__device__ __forceinline__ float dot4w(uint4 a, uint4 b) {
    float acc = 0.f;
    acc = bf16w_dot(a.x, b.x, acc);
    acc = bf16w_dot(a.y, b.y, acc);
    acc = bf16w_dot(a.z, b.z, acc);
    acc = bf16w_dot(a.w, b.w, acc);
    return acc;
}

__device__ __forceinline__ uint32_t f32_to_bf16_rne(float f) {
    uint32_t u = __float_as_uint(f);
    u += 0x7fffu + ((u >> 16) & 1u);   // round to nearest even
    return u >> 16;
}

// Each thread converts 8 consecutive f32 (one 32B chunk). Chunks 0..3 of a
// node go to hbA, 4..7 to hbB. Half-row = 32 bf16 = 16 uint32 words = 64B.
__global__ void convert_split(const float* __restrict__ h,
                              uint32_t* __restrict__ hbA,
                              uint32_t* __restrict__ hbB,
                              int n_chunks) {
    int i = blockIdx.x * blockDim.x + threadIdx.x;
    int stride = gridDim.x * blockDim.x;
    for (; i < n_chunks; i += stride) {
        const float4* p = reinterpret_cast<const float4*>(h) + (size_t)i * 2;
        float4 f0 = p[0];
        float4 f1 = p[1];
        uint4 w;
        w.x = f32_to_bf16_rne(f0.x) | (f32_to_bf16_rne(f0.y) << 16);
        w.y = f32_to_bf16_rne(f0.z) | (f32_to_bf16_rne(f0.w) << 16);
        w.z = f32_to_bf16_rne(f1.x) | (f32_to_bf16_rne(f1.y) << 16);
        w.w = f32_to_bf16_rne(f1.z) | (f32_to_bf16_rne(f1.w) << 16);
        int node = i >> 3;
        int c = i & 7;
        uint32_t* d = (c < 4) ? (hbA + (size_t)node * 16 + c * 4)
                              : (hbB + (size_t)node * 16 + (c - 4) * 4);
        *reinterpret_cast<uint4*>(d) = w;
    }
}

// One pass over a 3.2 MB half-table. 4 lanes/edge (lane sub loads uint4 #sub
// of the 64B half-row), 2 edges per group -> 4 gathers in flight per thread.
template <bool ACCUM>
__global__ void dot_half(const uint32_t* __restrict__ T,
                         const int* __restrict__ src,
                         const int* __restrict__ dst,
                         float* __restrict__ out,
                         int n_edges) {
    int gtid = blockIdx.x * blockDim.x + threadIdx.x;
    int group = gtid >> 2;
    int sub   = threadIdx.x & 3;
    int e0 = group * 2;
    if (e0 >= n_edges) return;
    int e1 = e0 + 1;
    bool has1 = (e1 < n_edges);

    int u0 = __builtin_nontemporal_load(&src[e0]);
    int v0 = __builtin_nontemporal_load(&dst[e0]);
    int u1 = has1 ? __builtin_nontemporal_load(&src[e1]) : u0;
    int v1 = has1 ? __builtin_nontemporal_load(&dst[e1]) : v0;

    uint4 a0 = reinterpret_cast<const uint4*>(T + (size_t)u0 * 16)[sub];
    uint4 b0 = reinterpret_cast<const uint4*>(T + (size_t)v0 * 16)[sub];
    uint4 a1 = reinterpret_cast<const uint4*>(T + (size_t)u1 * 16)[sub];
    uint4 b1 = reinterpret_cast<const uint4*>(T + (size_t)v1 * 16)[sub];

    float acc0 = dot4w(a0, b0);
    float acc1 = dot4w(a1, b1);

    acc0 += __shfl_xor(acc0, 1, 4);
    acc1 += __shfl_xor(acc1, 1, 4);
    acc0 += __shfl_xor(acc0, 2, 4);
    acc1 += __shfl_xor(acc1, 2, 4);

    if (sub == 0) {
        if (ACCUM) acc0 += __builtin_nontemporal_load(&out[e0]);
        __builtin_nontemporal_store(acc0, &out[e0]);
        if (has1) {
            if (ACCUM) acc1 += __builtin_nontemporal_load(&out[e1]);
            __builtin_nontemporal_store(acc1, &out[e1]);
        }
    }
}

// Fallback (f32 path, 16 lanes/edge) if workspace is too small.
__global__ void dot_edges_f32(const float* __restrict__ h,
                              const int* __restrict__ src,
                              const int* __restrict__ dst,
                              float* __restrict__ out,
                              int n_edges) {
    int gtid = blockIdx.x * blockDim.x + threadIdx.x;
    int edge = gtid >> 4;
    int sub  = threadIdx.x & 15;
    if (edge >= n_edges) return;

    int u = src[edge];
    int v = dst[edge];
    const float4* hu = reinterpret_cast<const float4*>(h + (size_t)u * 64);
    const float4* hv = reinterpret_cast<const float4*>(h + (size_t)v * 64);
    float4 a = hu[sub];
    float4 b = hv[sub];
    float acc = a.x * b.x + a.y * b.y + a.z * b.z + a.w * b.w;
    acc += __shfl_xor(acc, 1, 16);
    acc += __shfl_xor(acc, 2, 16);
    acc += __shfl_xor(acc, 4, 16);
    acc += __shfl_xor(acc, 8, 16);
    if (sub == 0) out[edge] = acc;
}

extern "C" void kernel_launch(void* const* d_in, const int* in_sizes, int n_in,
                              void* d_out, int out_size, void* d_ws, size_t ws_size,
                              hipStream_t stream) {
    const float* h   = (const float*)d_in[0];
    const int*   src = (const int*)d_in[1];
    const int*   dst = (const int*)d_in[2];
    float*       out = (float*)d_out;

    int n_edges = in_sizes[1];
    int n_feat_elems = in_sizes[0];            // n_nodes * 64
    int n_nodes = n_feat_elems / 64;
    size_t half_bytes = (size_t)n_nodes * 32 * 2;   // 32 bf16 * 2B = 64B/row
    size_t need = 2 * half_bytes;

    if (ws_size >= need) {
        uint32_t* hbA = (uint32_t*)d_ws;
        uint32_t* hbB = (uint32_t*)((char*)d_ws + half_bytes);

        int n_chunks = n_feat_elems / 8;
        int cthreads = 256;
        int cblocks = (n_chunks + cthreads - 1) / cthreads;
        if (cblocks > 2048) cblocks = 2048;
        convert_split<<<cblocks, cthreads, 0, stream>>>(h, hbA, hbB, n_chunks);

        const int threads = 256;
        // 4 lanes/group, 2 edges/group -> 128 edges per 256-thread block
        int n_groups = (n_edges + 1) / 2;
        int blocks = (n_groups * 4 + threads - 1) / threads;
        dot_half<false><<<blocks, threads, 0, stream>>>(hbA, src, dst, out, n_edges);
        dot_half<true ><<<blocks, threads, 0, stream>>>(hbB, src, dst, out, n_edges);
    } else {
        const int threads = 256;
        const int epb = threads / 16;
        int blocks = (n_edges + epb - 1) / epb;
        dot_edges_f32<<<blocks, threads, 0, stream>>>(h, src, dst, out, n_edges);
    }
}